// Round 15
// baseline (118.963 us; speedup 1.0000x reference)
//
#include <hip/hip_runtime.h>
#include <hip/hip_bf16.h>
#include <math.h>

#define BB 2
#define SS 2048
#define DD 1024
#define HH 16
#define HD 64
#define NEL (BB*SS*DD)

typedef __bf16 bf16;
typedef __bf16 bf16x8 __attribute__((ext_vector_type(8)));
typedef __bf16 bf16x4 __attribute__((ext_vector_type(4)));
typedef float  f32x4  __attribute__((ext_vector_type(4)));

#define LOG2E 1.4426950408889634f
#define QSCALE (0.125f * LOG2E)   // fold 1/sqrt(HD) and log2(e) into Q

#define GLOAD_LDS(gsrc, ldst) \
  __builtin_amdgcn_global_load_lds((const __attribute__((address_space(1))) void*)(gsrc), \
                                   (__attribute__((address_space(3))) void*)(ldst), 16, 0, 0)
#define WAIT_VM0()  asm volatile("s_waitcnt vmcnt(0)" ::: "memory")
#define WAIT_VM4()  asm volatile("s_waitcnt vmcnt(4)" ::: "memory")

// ---------------------------------------------------------------------------
// f32 -> bf16 bulk convert: q, k, v (NEL each) + 4 weight matrices.
// ---------------------------------------------------------------------------
__global__ __launch_bounds__(256)
void cvt_all(const float* __restrict__ s0, bf16* __restrict__ d0,
             const float* __restrict__ s1, bf16* __restrict__ d1,
             const float* __restrict__ s2, bf16* __restrict__ d2,
             const float* __restrict__ s3, bf16* __restrict__ d3,
             const float* __restrict__ s4, bf16* __restrict__ d4,
             const float* __restrict__ s5, bf16* __restrict__ d5,
             const float* __restrict__ s6, bf16* __restrict__ d6)
{
  const float* s; bf16* d; int n8;
  switch (blockIdx.y) {
    case 0: s = s0; d = d0; n8 = NEL/8; break;
    case 1: s = s1; d = d1; n8 = NEL/8; break;
    case 2: s = s2; d = d2; n8 = NEL/8; break;
    case 3: s = s3; d = d3; n8 = DD*DD/8; break;
    case 4: s = s4; d = d4; n8 = DD*DD/8; break;
    case 5: s = s5; d = d5; n8 = DD*DD/8; break;
    default: s = s6; d = d6; n8 = DD*DD/8; break;
  }
  for (int i = blockIdx.x*256 + threadIdx.x; i < n8; i += gridDim.x*256) {
    f32x4 a = ((const f32x4*)s)[2*i];
    f32x4 b = ((const f32x4*)s)[2*i + 1];
    bf16x8 o;
    o[0]=(bf16)a[0]; o[1]=(bf16)a[1]; o[2]=(bf16)a[2]; o[3]=(bf16)a[3];
    o[4]=(bf16)b[0]; o[5]=(bf16)b[1]; o[6]=(bf16)b[2]; o[7]=(bf16)b[3];
    ((bf16x8*)d)[i] = o;
  }
}

// ---------------------------------------------------------------------------
// bf16 GEMM core (128x64 out tile): 4 waves, DOUBLE-buffered global_load_lds
// (48 KB -> 3 blocks/CU; measured best for proj/gemm_out), chunk-XOR swizzle,
// one vmcnt(0)+barrier per K-step.
// ---------------------------------------------------------------------------
__device__ __forceinline__ void gemm_core(
    const bf16* __restrict__ A, const bf16* __restrict__ Bw,
    int bm, int bn, bf16 (&As)[2][128*64], bf16 (&Bs)[2][64*64],
    f32x4 (&acc)[4][2], int tid, int wid, int m0w, int n0w, int fr, int fq)
{
#define G_STAGE(k0, buf) do {                                              \
    _Pragma("unroll")                                                      \
    for (int i = 0; i < 4; ++i) {                                          \
      int qd = tid + 256*i;                                                \
      int j = qd >> 3, cp = qd & 7;                                        \
      GLOAD_LDS(A + (size_t)(bm + j)*DD + (k0) + ((cp ^ (j & 7)) << 3),    \
                &As[buf][(wid*64 + 256*i) << 3]);                          \
    }                                                                      \
    _Pragma("unroll")                                                      \
    for (int i = 0; i < 2; ++i) {                                          \
      int qd = tid + 256*i;                                                \
      int j = qd >> 3, cp = qd & 7;                                        \
      GLOAD_LDS(Bw + (size_t)(bn + j)*DD + (k0) + ((cp ^ (j & 7)) << 3),   \
                &Bs[buf][(wid*64 + 256*i) << 3]);                          \
    }                                                                      \
  } while (0)

  G_STAGE(0, 0);
  WAIT_VM0();
  __syncthreads();
  int cur = 0;

  for (int k0 = 0; k0 < DD; k0 += 64) {
    if (k0 + 64 < DD) G_STAGE(k0 + 64, cur ^ 1);

    #pragma unroll
    for (int kk = 0; kk < 2; ++kk) {
      bf16x8 a[4], b[2];
      #pragma unroll
      for (int mi = 0; mi < 4; ++mi) {
        int row = m0w + mi*16 + fr;
        a[mi] = *(const bf16x8*)&As[cur][row*64 + (((kk*4 + fq) ^ (fr & 7)) << 3)];
      }
      #pragma unroll
      for (int ni = 0; ni < 2; ++ni) {
        int row = n0w + ni*16 + fr;
        b[ni] = *(const bf16x8*)&Bs[cur][row*64 + (((kk*4 + fq) ^ (fr & 7)) << 3)];
      }
      __builtin_amdgcn_s_setprio(1);
      #pragma unroll
      for (int mi = 0; mi < 4; ++mi)
        #pragma unroll
        for (int ni = 0; ni < 2; ++ni)
          acc[mi][ni] = __builtin_amdgcn_mfma_f32_16x16x32_bf16(
              a[mi], b[ni], acc[mi][ni], 0, 0, 0);
      __builtin_amdgcn_s_setprio(0);
    }
    WAIT_VM0();
    __syncthreads();
    cur ^= 1;
  }
#undef G_STAGE
}

// ---------------------------------------------------------------------------
// Merged Q/K/V projection, 128x64 tiles, grid (16,32,3) = 1536 blocks,
// chunked bijective XCD remap (chunk 192).
// z=0: Qp row-major *QSCALE; z=1: Kp row-major; z=2: V^T per head with
// sigma-permuted columns: sigma(16n+4f+r) = 32(n>>1)+8f+4(n&1)+r.
// ---------------------------------------------------------------------------
__global__ __launch_bounds__(256)
void proj_qkv(const bf16* __restrict__ qb, const bf16* __restrict__ kb,
              const bf16* __restrict__ vb,
              const bf16* __restrict__ wq, const bf16* __restrict__ wk,
              const bf16* __restrict__ wv,
              bf16* __restrict__ Qp, bf16* __restrict__ Kp,
              bf16* __restrict__ Vtp)
{
  const int tid = threadIdx.x, lane = tid & 63, wid = tid >> 6;

  const int h = blockIdx.x + 16*(blockIdx.y + 32*blockIdx.z);
  const int d = (h & 7) * 192 + (h >> 3);
  const int zz = d >> 9;
  const int rem = d & 511;
  const int bm = (rem >> 4) * 128;
  const int bn = (rem & 15) * 64;

  const bf16 *A, *Bw; bf16* C; float scale; int mode;
  if (zz == 0)      { A = qb; Bw = wq; C = Qp;  scale = QSCALE; mode = 0; }
  else if (zz == 1) { A = kb; Bw = wk; C = Kp;  scale = 1.f;    mode = 0; }
  else              { A = vb; Bw = wv; C = Vtp; scale = 1.f;    mode = 1; }

  __shared__ bf16 As[2][128*64];
  __shared__ bf16 Bs[2][64*64];
  f32x4 acc[4][2] = {};
  const int m0w = (wid >> 1) * 64, n0w = (wid & 1) * 32;
  const int fr = lane & 15, fq = lane >> 4;

  gemm_core(A, Bw, bm, bn, As, Bs, acc, tid, wid, m0w, n0w, fr, fq);

  if (mode == 1) {
    #pragma unroll
    for (int mi = 0; mi < 4; ++mi) {
      int grow0 = bm + m0w + mi*16 + fq*4;
      int b = grow0 >> 11, s0 = grow0 & 2047;
      int s6 = s0 & 63;
      int sp = (s0 & ~63) | (((s6 >> 5) & 1) << 5) | (fq << 3) | (((s6 >> 4) & 1) << 2);
      #pragma unroll
      for (int ni = 0; ni < 2; ++ni) {
        int gcol = bn + n0w + ni*16 + fr;
        bf16x4 o;
        #pragma unroll
        for (int r = 0; r < 4; ++r) o[r] = (bf16)(acc[mi][ni][r] * scale);
        *(bf16x4*)&C[(((size_t)b*HH + (gcol >> 6))*HD + (gcol & 63))*SS + sp] = o;
      }
    }
  } else {
    #pragma unroll
    for (int mi = 0; mi < 4; ++mi)
      #pragma unroll
      for (int r = 0; r < 4; ++r) {
        int grow = bm + m0w + mi*16 + fq*4 + r;
        #pragma unroll
        for (int ni = 0; ni < 2; ++ni) {
          int gcol = bn + n0w + ni*16 + fr;
          C[(size_t)grow*DD + gcol] = (bf16)(acc[mi][ni][r] * scale);
        }
      }
  }
}

// ---------------------------------------------------------------------------
// Output projection -> f32, BN=64 (512 blocks), chunked XCD remap.
// ---------------------------------------------------------------------------
__global__ __launch_bounds__(256)
void gemm_out(const bf16* __restrict__ A, const bf16* __restrict__ Bw,
              float* __restrict__ C)
{
  const int tid = threadIdx.x, lane = tid & 63, wid = tid >> 6;

  const int h = blockIdx.x + 16*blockIdx.y;
  const int d = (h & 7) * 64 + (h >> 3);
  const int bm = (d >> 4) * 128;
  const int bn = (d & 15) * 64;

  __shared__ bf16 As[2][128*64];
  __shared__ bf16 Bs[2][64*64];
  f32x4 acc[4][2] = {};
  const int m0w = (wid >> 1) * 64, n0w = (wid & 1) * 32;
  const int fr = lane & 15, fq = lane >> 4;

  gemm_core(A, Bw, bm, bn, As, Bs, acc, tid, wid, m0w, n0w, fr, fq);

  #pragma unroll
  for (int mi = 0; mi < 4; ++mi)
    #pragma unroll
    for (int r = 0; r < 4; ++r) {
      int grow = bm + m0w + mi*16 + fq*4 + r;
      #pragma unroll
      for (int ni = 0; ni < 2; ++ni) {
        int gcol = bn + n0w + ni*16 + fr;
        C[(size_t)grow*DD + gcol] = acc[mi][ni][r];
      }
    }
}

// ---------------------------------------------------------------------------
// Fallback GEMM (A f32 or bf16, W f32 converted in staging). sigma'd mode 1.
// ---------------------------------------------------------------------------
template<bool A_F32, int OUT_MODE>
__global__ __launch_bounds__(256)
void gemm_abt(const void* __restrict__ Ap, const float* __restrict__ W,
              void* __restrict__ Cp, float scale)
{
  const int tid  = threadIdx.x;
  const int lane = tid & 63;
  const int wid  = tid >> 6;
  const int bm = blockIdx.y * 128;
  const int bn = blockIdx.x * 128;

  __shared__ bf16 As[128][72];
  __shared__ bf16 Bs[128][72];

  f32x4 acc[4][4] = {};
  const int m0w = (wid >> 1) * 64;
  const int n0w = (wid & 1) * 64;
  const int fr = lane & 15;
  const int fq = lane >> 4;

  for (int k0 = 0; k0 < DD; k0 += 64) {
    __syncthreads();
    if constexpr (A_F32) {
      const float* A = (const float*)Ap;
      #pragma unroll
      for (int p = 0; p < 8; ++p) {
        int row = p*16 + (tid >> 4);
        int col = (tid & 15) * 4;
        float4 v = *(const float4*)(A + (size_t)(bm + row)*DD + k0 + col);
        bf16x4 hh; hh[0]=(bf16)v.x; hh[1]=(bf16)v.y; hh[2]=(bf16)v.z; hh[3]=(bf16)v.w;
        *(bf16x4*)&As[row][col] = hh;
      }
    } else {
      const bf16* A = (const bf16*)Ap;
      #pragma unroll
      for (int p = 0; p < 4; ++p) {
        int row = p*32 + (tid >> 3);
        int col = (tid & 7) * 8;
        *(bf16x8*)&As[row][col] = *(const bf16x8*)(A + (size_t)(bm + row)*DD + k0 + col);
      }
    }
    #pragma unroll
    for (int p = 0; p < 8; ++p) {
      int row = p*16 + (tid >> 4);
      int col = (tid & 15) * 4;
      float4 v = *(const float4*)(W + (size_t)(bn + row)*DD + k0 + col);
      bf16x4 hh; hh[0]=(bf16)v.x; hh[1]=(bf16)v.y; hh[2]=(bf16)v.z; hh[3]=(bf16)v.w;
      *(bf16x4*)&Bs[row][col] = hh;
    }
    __syncthreads();

    #pragma unroll
    for (int kk = 0; kk < 2; ++kk) {
      bf16x8 a[4], b[4];
      #pragma unroll
      for (int mi = 0; mi < 4; ++mi)
        a[mi] = *(const bf16x8*)&As[m0w + mi*16 + fr][kk*32 + fq*8];
      #pragma unroll
      for (int ni = 0; ni < 4; ++ni)
        b[ni] = *(const bf16x8*)&Bs[n0w + ni*16 + fr][kk*32 + fq*8];
      #pragma unroll
      for (int mi = 0; mi < 4; ++mi)
        #pragma unroll
        for (int ni = 0; ni < 4; ++ni)
          acc[mi][ni] = __builtin_amdgcn_mfma_f32_16x16x32_bf16(
              a[mi], b[ni], acc[mi][ni], 0, 0, 0);
    }
  }

  if constexpr (OUT_MODE == 1) {
    bf16* Vt = (bf16*)Cp;
    #pragma unroll
    for (int mi = 0; mi < 4; ++mi) {
      int grow0 = bm + m0w + mi*16 + fq*4;
      int b = grow0 >> 11, s0 = grow0 & 2047;
      int s6 = s0 & 63;
      int sp = (s0 & ~63) | (((s6 >> 5) & 1) << 5) | (fq << 3) | (((s6 >> 4) & 1) << 2);
      #pragma unroll
      for (int ni = 0; ni < 4; ++ni) {
        int gcol = bn + n0w + ni*16 + fr;
        bf16x4 o;
        #pragma unroll
        for (int r = 0; r < 4; ++r) o[r] = (bf16)(acc[mi][ni][r] * scale);
        *(bf16x4*)&Vt[(((size_t)b*HH + (gcol >> 6))*HD + (gcol & 63))*SS + sp] = o;
      }
    }
  } else {
    #pragma unroll
    for (int mi = 0; mi < 4; ++mi) {
      #pragma unroll
      for (int r = 0; r < 4; ++r) {
        int grow = bm + m0w + mi*16 + fq*4 + r;
        #pragma unroll
        for (int ni = 0; ni < 4; ++ni) {
          int gcol = bn + n0w + ni*16 + fr;
          float v = acc[mi][ni][r] * scale;
          if constexpr (OUT_MODE == 2)
            ((float*)Cp)[(size_t)grow*DD + gcol] = v;
          else
            ((bf16*)Cp)[(size_t)grow*DD + gcol] = (bf16)v;
        }
      }
    }
  }
}

// ---------------------------------------------------------------------------
// Causal flash attention — r13 internals (triple-buffer K/V, counted vmcnt,
// ones-MFMA row-sums) with EQUAL-DURATION CO-RESIDENCY mapping: each CU's
// two blocks have the SAME p (same KT), so both stay resident the full
// duration -> 8 waves/CU throughout (fixes the big+small pairing where the
// small block exited early leaving 1 wave/SIMD, measured Occ=11%).
// Slot l pairs with l+1 (depth-first assignment) AND l+32 (breadth-first):
// both give equal p, different heads. 4 heads per XCD preserved.
// ---------------------------------------------------------------------------
__global__ __launch_bounds__(256)
void attn_fwd(const bf16* __restrict__ Q, const bf16* __restrict__ Kp,
              const bf16* __restrict__ Vt, bf16* __restrict__ O)
{
  const int tid = threadIdx.x, lane = tid & 63, w = tid >> 6;
  const int fr = lane & 15, fq = lane >> 4;

  int linear = blockIdx.x + (int)gridDim.x * blockIdx.y;   // 0..511
  int xcd = linear & 7, l = linear >> 3;                    // l 0..63
  int p  = (l & 31) >> 1;                                   // q-tile 0..15, equal for CU-pairs
  int hl = (l & 1) | ((l >> 5) << 1);                       // head slot 0..3
  int bh = xcd + 8*hl;                                      // 0..31
  const int b = bh >> 4, h = bh & 15;
  const int q0 = p * 128;
  const int KT = 2*p + 2;                                   // kv tiles (>=2)

  __shared__ bf16 Ks[3][64*64];
  __shared__ bf16 Vs[3][64*64];

  const size_t baseQ = (size_t)b*SS*DD + (size_t)h*HD;
  const bf16* Kb = Kp + baseQ;
  const bf16* Vh = Vt + (size_t)bh*HD*SS;   // [64 d][2048 s], sigma'd per 64

  const int wq0 = q0 + 32*w;                // wave's first q-row
  int myq[2];
  bf16x8 qf[2][2];
  #pragma unroll
  for (int u = 0; u < 2; ++u) {
    myq[u] = wq0 + 16*u + fr;
    #pragma unroll
    for (int kk = 0; kk < 2; ++kk)
      qf[u][kk] = *(const bf16x8*)(Q + baseQ + (size_t)myq[u]*DD + kk*32 + fq*8);
  }

  bf16x8 ones;
  #pragma unroll
  for (int e = 0; e < 8; ++e) ones[e] = (bf16)1.0f;

  f32x4 oacc[2][4] = {};
  f32x4 lacc[2] = {};

#define ATTN_STAGE(kv, buf) do { _Pragma("unroll")                           \
  for (int i = 0; i < 2; ++i) {                                              \
    int qd = tid + 256*i; int j = qd >> 3, cp = qd & 7;                      \
    int cg = (cp ^ (j & 7)) << 3;                                            \
    GLOAD_LDS(Kb + (size_t)((kv) + j)*DD + cg, &Ks[buf][(w*64 + 256*i) << 3]); \
    GLOAD_LDS(Vh + (size_t)j*SS + (kv) + cg,   &Vs[buf][(w*64 + 256*i) << 3]); \
  } } while (0)

  ATTN_STAGE(0, 0);       // KT >= 2 always
  ATTN_STAGE(64, 1);
  int cur = 0;

  for (int kt = 0; kt < KT; ++kt) {
    if (kt + 1 < KT) WAIT_VM4(); else WAIT_VM0();   // stage(kt) complete
    __syncthreads();
    if (kt + 2 < KT) {
      int b2 = cur - 1; if (b2 < 0) b2 = 2;         // (kt+2) % 3
      ATTN_STAGE((kt + 2)*64, b2);
    }

    if (kt*64 <= wq0 + 31) {   // wave-uniform: some of this wave's rows unmasked
      // ---- S^T = K @ Q^T : K fragments shared across both 16-row groups ----
      f32x4 sacc[2][4] = {};
      #pragma unroll
      for (int kk = 0; kk < 2; ++kk) {
        bf16x8 bk[4];
        #pragma unroll
        for (int ni = 0; ni < 4; ++ni)
          bk[ni] = *(const bf16x8*)&Ks[cur][(ni*16 + fr)*64 + (((kk*4 + fq) ^ (fr & 7)) << 3)];
        __builtin_amdgcn_s_setprio(1);
        #pragma unroll
        for (int ni = 0; ni < 4; ++ni) {
          sacc[0][ni] = __builtin_amdgcn_mfma_f32_16x16x32_bf16(bk[ni], qf[0][kk], sacc[0][ni], 0,0,0);
          sacc[1][ni] = __builtin_amdgcn_mfma_f32_16x16x32_bf16(bk[ni], qf[1][kk], sacc[1][ni], 0,0,0);
        }
        __builtin_amdgcn_s_setprio(0);
      }

      // ---- causal mask where tile overlaps a group's rows ----
      #pragma unroll
      for (int u = 0; u < 2; ++u)
        if (kt*64 + 63 > wq0 + 16*u) {
          #pragma unroll
          for (int ni = 0; ni < 4; ++ni) {
            int kg = kt*64 + ni*16 + fq*4;
            #pragma unroll
            for (int r = 0; r < 4; ++r)
              if (kg + r > myq[u]) sacc[u][ni][r] = -1e30f;
          }
        }

      // ---- P = exp2(S^T) into A-fragments ----
      bf16x8 pa[2][2];
      #pragma unroll
      for (int u = 0; u < 2; ++u)
        #pragma unroll
        for (int kk = 0; kk < 2; ++kk)
          #pragma unroll
          for (int e = 0; e < 8; ++e)
            pa[u][kk][e] = (bf16)__builtin_amdgcn_exp2f(sacc[u][2*kk + (e >> 2)][e & 3]);

      // ---- O += P @ V ; l += P @ 1 (V fragments shared across groups) ----
      #pragma unroll
      for (int kk = 0; kk < 2; ++kk) {
        bf16x8 bv[4];
        #pragma unroll
        for (int nf = 0; nf < 4; ++nf)
          bv[nf] = *(const bf16x8*)&Vs[cur][(nf*16 + fr)*64 + (((4*kk + fq) ^ (fr & 7)) << 3)];
        __builtin_amdgcn_s_setprio(1);
        lacc[0] = __builtin_amdgcn_mfma_f32_16x16x32_bf16(pa[0][kk], ones, lacc[0], 0,0,0);
        lacc[1] = __builtin_amdgcn_mfma_f32_16x16x32_bf16(pa[1][kk], ones, lacc[1], 0,0,0);
        #pragma unroll
        for (int nf = 0; nf < 4; ++nf) {
          oacc[0][nf] = __builtin_amdgcn_mfma_f32_16x16x32_bf16(pa[0][kk], bv[nf], oacc[0][nf], 0,0,0);
          oacc[1][nf] = __builtin_amdgcn_mfma_f32_16x16x32_bf16(pa[1][kk], bv[nf], oacc[1][nf], 0,0,0);
        }
        __builtin_amdgcn_s_setprio(0);
      }
    }

    cur = (cur + 1 == 3) ? 0 : cur + 1;
  }
#undef ATTN_STAGE

  // ---- epilogue: lacc[u][r] is l for exactly oacc's row — no shuffles ----
  #pragma unroll
  for (int u = 0; u < 2; ++u) {
    const int row0 = wq0 + 16*u + fq*4;
    #pragma unroll
    for (int r = 0; r < 4; ++r) {
      float inv = 1.f / lacc[u][r];
      int s = row0 + r;
      #pragma unroll
      for (int nf = 0; nf < 4; ++nf)
        O[baseQ + (size_t)s*DD + nf*16 + fr] = (bf16)(oacc[u][nf][r] * inv);
    }
  }
}

// ---------------------------------------------------------------------------
extern "C" void kernel_launch(void* const* d_in, const int* in_sizes, int n_in,
                              void* d_out, int out_size, void* d_ws, size_t ws_size,
                              hipStream_t stream)
{
  const float* q   = (const float*)d_in[0];
  const float* k   = (const float*)d_in[1];
  const float* v   = (const float*)d_in[2];
  const float* w_q = (const float*)d_in[4];
  const float* w_k = (const float*)d_in[5];
  const float* w_v = (const float*)d_in[6];
  const float* w_o = (const float*)d_in[7];
  float* out = (float*)d_out;

  dim3 blk(256);
  const size_t need = ((size_t)4*NEL + (size_t)4*DD*DD) * sizeof(bf16); // ~41.9 MB

  if (ws_size >= need) {
    bf16* qb  = (bf16*)d_out;
    bf16* kb  = qb + NEL;
    bf16* vb  = (bf16*)d_ws;
    bf16* wqb = vb + NEL;
    bf16* wkb = wqb + DD*DD;
    bf16* wvb = wkb + DD*DD;
    bf16* wob = wvb + DD*DD;
    bf16* Qp  = wob + DD*DD;
    bf16* Kp  = Qp + NEL;
    bf16* Vtp = Kp + NEL;
    bf16* At  = vb;   // vb dead after V-projection

    cvt_all<<<dim3(512, 7), blk, 0, stream>>>(q, qb, k, kb, v, vb,
                                              w_q, wqb, w_k, wkb, w_v, wvb, w_o, wob);
    proj_qkv<<<dim3(16, 32, 3), blk, 0, stream>>>(
        qb, kb, vb, wqb, wkb, wvb, Qp, Kp, Vtp);
    attn_fwd<<<dim3(16, 32), blk, 0, stream>>>(Qp, Kp, Vtp, At);
    gemm_out<<<dim3(DD/64, (BB*SS)/128), blk, 0, stream>>>(At, wob, out);
  } else {
    bf16* Qp  = (bf16*)d_ws;
    bf16* Kp  = Qp + NEL;
    bf16* Vtp = Kp + NEL;
    bf16* At  = Qp;

    dim3 gg(DD/128, (BB*SS)/128);
    gemm_abt<true, 0><<<gg, blk, 0, stream>>>(q, w_q, Qp, QSCALE);
    gemm_abt<true, 0><<<gg, blk, 0, stream>>>(k, w_k, Kp, 1.0f);
    gemm_abt<true, 1><<<gg, blk, 0, stream>>>(v, w_v, Vtp, 1.0f);
    attn_fwd<<<dim3(16, 32), blk, 0, stream>>>(Qp, Kp, Vtp, At);
    gemm_abt<false, 2><<<gg, blk, 0, stream>>>(At, w_o, out, 1.0f);
  }
}

// Round 16
// 107.663 us; speedup vs baseline: 1.1050x; 1.1050x over previous
//
#include <hip/hip_runtime.h>
#include <hip/hip_bf16.h>
#include <math.h>

#define BB 2
#define SS 2048
#define DD 1024
#define HH 16
#define HD 64
#define NEL (BB*SS*DD)

typedef __bf16 bf16;
typedef __bf16 bf16x8 __attribute__((ext_vector_type(8)));
typedef __bf16 bf16x4 __attribute__((ext_vector_type(4)));
typedef float  f32x4  __attribute__((ext_vector_type(4)));

#define LOG2E 1.4426950408889634f
#define QSCALE (0.125f * LOG2E)   // fold 1/sqrt(HD) and log2(e) into Q

#define GLOAD_LDS(gsrc, ldst) \
  __builtin_amdgcn_global_load_lds((const __attribute__((address_space(1))) void*)(gsrc), \
                                   (__attribute__((address_space(3))) void*)(ldst), 16, 0, 0)
#define WAIT_VM0()  asm volatile("s_waitcnt vmcnt(0)" ::: "memory")

// ---------------------------------------------------------------------------
// f32 -> bf16 bulk convert: q, k, v (NEL each) + 4 weight matrices.
// ---------------------------------------------------------------------------
__global__ __launch_bounds__(256)
void cvt_all(const float* __restrict__ s0, bf16* __restrict__ d0,
             const float* __restrict__ s1, bf16* __restrict__ d1,
             const float* __restrict__ s2, bf16* __restrict__ d2,
             const float* __restrict__ s3, bf16* __restrict__ d3,
             const float* __restrict__ s4, bf16* __restrict__ d4,
             const float* __restrict__ s5, bf16* __restrict__ d5,
             const float* __restrict__ s6, bf16* __restrict__ d6)
{
  const float* s; bf16* d; int n8;
  switch (blockIdx.y) {
    case 0: s = s0; d = d0; n8 = NEL/8; break;
    case 1: s = s1; d = d1; n8 = NEL/8; break;
    case 2: s = s2; d = d2; n8 = NEL/8; break;
    case 3: s = s3; d = d3; n8 = DD*DD/8; break;
    case 4: s = s4; d = d4; n8 = DD*DD/8; break;
    case 5: s = s5; d = d5; n8 = DD*DD/8; break;
    default: s = s6; d = d6; n8 = DD*DD/8; break;
  }
  for (int i = blockIdx.x*256 + threadIdx.x; i < n8; i += gridDim.x*256) {
    f32x4 a = ((const f32x4*)s)[2*i];
    f32x4 b = ((const f32x4*)s)[2*i + 1];
    bf16x8 o;
    o[0]=(bf16)a[0]; o[1]=(bf16)a[1]; o[2]=(bf16)a[2]; o[3]=(bf16)a[3];
    o[4]=(bf16)b[0]; o[5]=(bf16)b[1]; o[6]=(bf16)b[2]; o[7]=(bf16)b[3];
    ((bf16x8*)d)[i] = o;
  }
}

// ---------------------------------------------------------------------------
// bf16 GEMM core (128x64 out tile): 4 waves, DOUBLE-buffered global_load_lds
// (48 KB -> 3 blocks/CU; measured best), chunk-XOR swizzle, one
// vmcnt(0)+barrier per K-step.
// ---------------------------------------------------------------------------
__device__ __forceinline__ void gemm_core(
    const bf16* __restrict__ A, const bf16* __restrict__ Bw,
    int bm, int bn, bf16 (&As)[2][128*64], bf16 (&Bs)[2][64*64],
    f32x4 (&acc)[4][2], int tid, int wid, int m0w, int n0w, int fr, int fq)
{
#define G_STAGE(k0, buf) do {                                              \
    _Pragma("unroll")                                                      \
    for (int i = 0; i < 4; ++i) {                                          \
      int qd = tid + 256*i;                                                \
      int j = qd >> 3, cp = qd & 7;                                        \
      GLOAD_LDS(A + (size_t)(bm + j)*DD + (k0) + ((cp ^ (j & 7)) << 3),    \
                &As[buf][(wid*64 + 256*i) << 3]);                          \
    }                                                                      \
    _Pragma("unroll")                                                      \
    for (int i = 0; i < 2; ++i) {                                          \
      int qd = tid + 256*i;                                                \
      int j = qd >> 3, cp = qd & 7;                                        \
      GLOAD_LDS(Bw + (size_t)(bn + j)*DD + (k0) + ((cp ^ (j & 7)) << 3),   \
                &Bs[buf][(wid*64 + 256*i) << 3]);                          \
    }                                                                      \
  } while (0)

  G_STAGE(0, 0);
  WAIT_VM0();
  __syncthreads();
  int cur = 0;

  for (int k0 = 0; k0 < DD; k0 += 64) {
    if (k0 + 64 < DD) G_STAGE(k0 + 64, cur ^ 1);

    #pragma unroll
    for (int kk = 0; kk < 2; ++kk) {
      bf16x8 a[4], b[2];
      #pragma unroll
      for (int mi = 0; mi < 4; ++mi) {
        int row = m0w + mi*16 + fr;
        a[mi] = *(const bf16x8*)&As[cur][row*64 + (((kk*4 + fq) ^ (fr & 7)) << 3)];
      }
      #pragma unroll
      for (int ni = 0; ni < 2; ++ni) {
        int row = n0w + ni*16 + fr;
        b[ni] = *(const bf16x8*)&Bs[cur][row*64 + (((kk*4 + fq) ^ (fr & 7)) << 3)];
      }
      __builtin_amdgcn_s_setprio(1);
      #pragma unroll
      for (int mi = 0; mi < 4; ++mi)
        #pragma unroll
        for (int ni = 0; ni < 2; ++ni)
          acc[mi][ni] = __builtin_amdgcn_mfma_f32_16x16x32_bf16(
              a[mi], b[ni], acc[mi][ni], 0, 0, 0);
      __builtin_amdgcn_s_setprio(0);
    }
    WAIT_VM0();
    __syncthreads();
    cur ^= 1;
  }
#undef G_STAGE
}

// ---------------------------------------------------------------------------
// Merged Q/K/V projection, 128x64 tiles, grid (16,32,3) = 1536 blocks,
// chunked bijective XCD remap (chunk 192).
// z=0: Qp row-major *QSCALE; z=1: Kp row-major; z=2: V^T per head with
// sigma-permuted columns: sigma(16n+4f+r) = 32(n>>1)+8f+4(n&1)+r.
// ---------------------------------------------------------------------------
__global__ __launch_bounds__(256)
void proj_qkv(const bf16* __restrict__ qb, const bf16* __restrict__ kb,
              const bf16* __restrict__ vb,
              const bf16* __restrict__ wq, const bf16* __restrict__ wk,
              const bf16* __restrict__ wv,
              bf16* __restrict__ Qp, bf16* __restrict__ Kp,
              bf16* __restrict__ Vtp)
{
  const int tid = threadIdx.x, lane = tid & 63, wid = tid >> 6;

  const int h = blockIdx.x + 16*(blockIdx.y + 32*blockIdx.z);
  const int d = (h & 7) * 192 + (h >> 3);
  const int zz = d >> 9;
  const int rem = d & 511;
  const int bm = (rem >> 4) * 128;
  const int bn = (rem & 15) * 64;

  const bf16 *A, *Bw; bf16* C; float scale; int mode;
  if (zz == 0)      { A = qb; Bw = wq; C = Qp;  scale = QSCALE; mode = 0; }
  else if (zz == 1) { A = kb; Bw = wk; C = Kp;  scale = 1.f;    mode = 0; }
  else              { A = vb; Bw = wv; C = Vtp; scale = 1.f;    mode = 1; }

  __shared__ bf16 As[2][128*64];
  __shared__ bf16 Bs[2][64*64];
  f32x4 acc[4][2] = {};
  const int m0w = (wid >> 1) * 64, n0w = (wid & 1) * 32;
  const int fr = lane & 15, fq = lane >> 4;

  gemm_core(A, Bw, bm, bn, As, Bs, acc, tid, wid, m0w, n0w, fr, fq);

  if (mode == 1) {
    #pragma unroll
    for (int mi = 0; mi < 4; ++mi) {
      int grow0 = bm + m0w + mi*16 + fq*4;
      int b = grow0 >> 11, s0 = grow0 & 2047;
      int s6 = s0 & 63;
      int sp = (s0 & ~63) | (((s6 >> 5) & 1) << 5) | (fq << 3) | (((s6 >> 4) & 1) << 2);
      #pragma unroll
      for (int ni = 0; ni < 2; ++ni) {
        int gcol = bn + n0w + ni*16 + fr;
        bf16x4 o;
        #pragma unroll
        for (int r = 0; r < 4; ++r) o[r] = (bf16)(acc[mi][ni][r] * scale);
        *(bf16x4*)&C[(((size_t)b*HH + (gcol >> 6))*HD + (gcol & 63))*SS + sp] = o;
      }
    }
  } else {
    #pragma unroll
    for (int mi = 0; mi < 4; ++mi)
      #pragma unroll
      for (int r = 0; r < 4; ++r) {
        int grow = bm + m0w + mi*16 + fq*4 + r;
        #pragma unroll
        for (int ni = 0; ni < 2; ++ni) {
          int gcol = bn + n0w + ni*16 + fr;
          C[(size_t)grow*DD + gcol] = (bf16)(acc[mi][ni][r] * scale);
        }
      }
  }
}

// ---------------------------------------------------------------------------
// Output projection -> f32, BN=64 (512 blocks), chunked XCD remap.
// ---------------------------------------------------------------------------
__global__ __launch_bounds__(256)
void gemm_out(const bf16* __restrict__ A, const bf16* __restrict__ Bw,
              float* __restrict__ C)
{
  const int tid = threadIdx.x, lane = tid & 63, wid = tid >> 6;

  const int h = blockIdx.x + 16*blockIdx.y;
  const int d = (h & 7) * 64 + (h >> 3);
  const int bm = (d >> 4) * 128;
  const int bn = (d & 15) * 64;

  __shared__ bf16 As[2][128*64];
  __shared__ bf16 Bs[2][64*64];
  f32x4 acc[4][2] = {};
  const int m0w = (wid >> 1) * 64, n0w = (wid & 1) * 32;
  const int fr = lane & 15, fq = lane >> 4;

  gemm_core(A, Bw, bm, bn, As, Bs, acc, tid, wid, m0w, n0w, fr, fq);

  #pragma unroll
  for (int mi = 0; mi < 4; ++mi)
    #pragma unroll
    for (int r = 0; r < 4; ++r) {
      int grow = bm + m0w + mi*16 + fq*4 + r;
      #pragma unroll
      for (int ni = 0; ni < 2; ++ni) {
        int gcol = bn + n0w + ni*16 + fr;
        C[(size_t)grow*DD + gcol] = acc[mi][ni][r];
      }
    }
}

// ---------------------------------------------------------------------------
// Fallback GEMM (A f32 or bf16, W f32 converted in staging). sigma'd mode 1.
// ---------------------------------------------------------------------------
template<bool A_F32, int OUT_MODE>
__global__ __launch_bounds__(256)
void gemm_abt(const void* __restrict__ Ap, const float* __restrict__ W,
              void* __restrict__ Cp, float scale)
{
  const int tid  = threadIdx.x;
  const int lane = tid & 63;
  const int wid  = tid >> 6;
  const int bm = blockIdx.y * 128;
  const int bn = blockIdx.x * 128;

  __shared__ bf16 As[128][72];
  __shared__ bf16 Bs[128][72];

  f32x4 acc[4][4] = {};
  const int m0w = (wid >> 1) * 64;
  const int n0w = (wid & 1) * 64;
  const int fr = lane & 15;
  const int fq = lane >> 4;

  for (int k0 = 0; k0 < DD; k0 += 64) {
    __syncthreads();
    if constexpr (A_F32) {
      const float* A = (const float*)Ap;
      #pragma unroll
      for (int p = 0; p < 8; ++p) {
        int row = p*16 + (tid >> 4);
        int col = (tid & 15) * 4;
        float4 v = *(const float4*)(A + (size_t)(bm + row)*DD + k0 + col);
        bf16x4 hh; hh[0]=(bf16)v.x; hh[1]=(bf16)v.y; hh[2]=(bf16)v.z; hh[3]=(bf16)v.w;
        *(bf16x4*)&As[row][col] = hh;
      }
    } else {
      const bf16* A = (const bf16*)Ap;
      #pragma unroll
      for (int p = 0; p < 4; ++p) {
        int row = p*32 + (tid >> 3);
        int col = (tid & 7) * 8;
        *(bf16x8*)&As[row][col] = *(const bf16x8*)(A + (size_t)(bm + row)*DD + k0 + col);
      }
    }
    #pragma unroll
    for (int p = 0; p < 8; ++p) {
      int row = p*16 + (tid >> 4);
      int col = (tid & 15) * 4;
      float4 v = *(const float4*)(W + (size_t)(bn + row)*DD + k0 + col);
      bf16x4 hh; hh[0]=(bf16)v.x; hh[1]=(bf16)v.y; hh[2]=(bf16)v.z; hh[3]=(bf16)v.w;
      *(bf16x4*)&Bs[row][col] = hh;
    }
    __syncthreads();

    #pragma unroll
    for (int kk = 0; kk < 2; ++kk) {
      bf16x8 a[4], b[4];
      #pragma unroll
      for (int mi = 0; mi < 4; ++mi)
        a[mi] = *(const bf16x8*)&As[m0w + mi*16 + fr][kk*32 + fq*8];
      #pragma unroll
      for (int ni = 0; ni < 4; ++ni)
        b[ni] = *(const bf16x8*)&Bs[n0w + ni*16 + fr][kk*32 + fq*8];
      #pragma unroll
      for (int mi = 0; mi < 4; ++mi)
        #pragma unroll
        for (int ni = 0; ni < 4; ++ni)
          acc[mi][ni] = __builtin_amdgcn_mfma_f32_16x16x32_bf16(
              a[mi], b[ni], acc[mi][ni], 0, 0, 0);
    }
  }

  if constexpr (OUT_MODE == 1) {
    bf16* Vt = (bf16*)Cp;
    #pragma unroll
    for (int mi = 0; mi < 4; ++mi) {
      int grow0 = bm + m0w + mi*16 + fq*4;
      int b = grow0 >> 11, s0 = grow0 & 2047;
      int s6 = s0 & 63;
      int sp = (s0 & ~63) | (((s6 >> 5) & 1) << 5) | (fq << 3) | (((s6 >> 4) & 1) << 2);
      #pragma unroll
      for (int ni = 0; ni < 4; ++ni) {
        int gcol = bn + n0w + ni*16 + fr;
        bf16x4 o;
        #pragma unroll
        for (int r = 0; r < 4; ++r) o[r] = (bf16)(acc[mi][ni][r] * scale);
        *(bf16x4*)&Vt[(((size_t)b*HH + (gcol >> 6))*HD + (gcol & 63))*SS + sp] = o;
      }
    }
  } else {
    #pragma unroll
    for (int mi = 0; mi < 4; ++mi) {
      #pragma unroll
      for (int r = 0; r < 4; ++r) {
        int grow = bm + m0w + mi*16 + fq*4 + r;
        #pragma unroll
        for (int ni = 0; ni < 4; ++ni) {
          int gcol = bn + n0w + ni*16 + fr;
          float v = acc[mi][ni][r] * scale;
          if constexpr (OUT_MODE == 2)
            ((float*)Cp)[(size_t)grow*DD + gcol] = v;
          else
            ((bf16*)Cp)[(size_t)grow*DD + gcol] = (bf16)v;
        }
      }
    }
  }
}

// ---------------------------------------------------------------------------
// Causal flash attention — KVBLK=128 amortization: r8 geometry/mapping
// (128-row q-tiles, 4 waves x 32 q-rows, 512 blocks, balanced big+small
// pairs), but each pipeline step stages a 128-row K/V CHUNK (32 KB) and
// computes two 64-sub-tiles back-to-back. Steps, barriers, and drains halve;
// the per-step MFMA chain doubles (more ILP for the often-single wave/SIMD).
// LDS 64 KB double-buffered — free (grid-limited 2 blocks/CU).
// ones-MFMA row-sums, shuffle-free epilogue.
// ---------------------------------------------------------------------------
__global__ __launch_bounds__(256)
void attn_fwd(const bf16* __restrict__ Q, const bf16* __restrict__ Kp,
              const bf16* __restrict__ Vt, bf16* __restrict__ O)
{
  const int tid = threadIdx.x, lane = tid & 63, w = tid >> 6;
  const int fr = lane & 15, fq = lane >> 4;

  // r8 mapping: per XCD 64 = {4 heads x 8 big p} then {4 heads x 8 small p}
  int linear = blockIdx.x + (int)gridDim.x * blockIdx.y;   // 0..511
  int xcd = linear & 7, l = linear >> 3;                    // l 0..63
  int half = l >> 5, li = l & 31;
  int hl = li >> 3, jj = li & 7;
  int p = half ? jj : (15 - jj);                            // q-tile 0..15
  int bh = xcd + 8*hl;                                      // 0..31
  const int b = bh >> 4, h = bh & 15;
  const int q0 = p * 128;
  const int CT = p + 1;                                     // 128-row kv chunks

  __shared__ bf16 Ks[2][128*64];      // [buf][row 0..127][64 k], swizzled
  __shared__ bf16 Vs[2][2*64*64];     // [buf][sub 0..1][64 d][64 s], swizzled

  const size_t baseQ = (size_t)b*SS*DD + (size_t)h*HD;
  const bf16* Kb = Kp + baseQ;
  const bf16* Vh = Vt + (size_t)bh*HD*SS;   // [64 d][2048 s], sigma'd per 64

  const int wq0 = q0 + 32*w;                // wave's first q-row
  int myq[2];
  bf16x8 qf[2][2];
  #pragma unroll
  for (int u = 0; u < 2; ++u) {
    myq[u] = wq0 + 16*u + fr;
    #pragma unroll
    for (int kk = 0; kk < 2; ++kk)
      qf[u][kk] = *(const bf16x8*)(Q + baseQ + (size_t)myq[u]*DD + kk*32 + fq*8);
  }

  bf16x8 ones;
  #pragma unroll
  for (int e = 0; e < 8; ++e) ones[e] = (bf16)1.0f;

  f32x4 oacc[2][4] = {};
  f32x4 lacc[2] = {};

  // Stage a 128-row K chunk + two 64-col V sub-tiles (8 loads/thread, 32 KB)
#define ATTN_STAGE(kv, buf) do {                                               \
    _Pragma("unroll")                                                          \
    for (int i = 0; i < 4; ++i) {          /* K: rows 0..127 */                \
      int qd = tid + 256*i; int j = qd >> 3, cp = qd & 7;                      \
      int cg = (cp ^ (j & 7)) << 3;                                            \
      GLOAD_LDS(Kb + (size_t)((kv) + j)*DD + cg,                               \
                &Ks[buf][(w*64 + 256*i) << 3]);                                \
    }                                                                          \
    _Pragma("unroll")                                                          \
    for (int i = 0; i < 4; ++i) {          /* V: 2 sub-tiles x 64 d-rows */    \
      int ii = i & 1, sub = i >> 1;                                            \
      int qd = tid + 256*ii; int j = qd >> 3, cp = qd & 7;                     \
      int cg = (cp ^ (j & 7)) << 3;                                            \
      GLOAD_LDS(Vh + (size_t)j*SS + (kv) + 64*sub + cg,                        \
                &Vs[buf][sub*4096 + ((w*64 + 256*ii) << 3)]);                  \
    }                                                                          \
  } while (0)

  ATTN_STAGE(0, 0);
  WAIT_VM0();
  __syncthreads();
  int cur = 0;

  for (int ct = 0; ct < CT; ++ct) {
    if (ct + 1 < CT) ATTN_STAGE((ct + 1)*128, cur ^ 1);

    #pragma unroll
    for (int sub = 0; sub < 2; ++sub) {
      const int kv0 = ct*128 + sub*64;
      if (kv0 > wq0 + 31) continue;     // wave-uniform causal skip

      // ---- S^T = K @ Q^T : K fragments shared across both 16-row groups ---
      f32x4 sacc[2][4] = {};
      #pragma unroll
      for (int kk = 0; kk < 2; ++kk) {
        bf16x8 bk[4];
        #pragma unroll
        for (int ni = 0; ni < 4; ++ni) {
          int row = sub*64 + ni*16 + fr;
          bk[ni] = *(const bf16x8*)&Ks[cur][row*64 + (((kk*4 + fq) ^ (fr & 7)) << 3)];
        }
        __builtin_amdgcn_s_setprio(1);
        #pragma unroll
        for (int ni = 0; ni < 4; ++ni) {
          sacc[0][ni] = __builtin_amdgcn_mfma_f32_16x16x32_bf16(bk[ni], qf[0][kk], sacc[0][ni], 0,0,0);
          sacc[1][ni] = __builtin_amdgcn_mfma_f32_16x16x32_bf16(bk[ni], qf[1][kk], sacc[1][ni], 0,0,0);
        }
        __builtin_amdgcn_s_setprio(0);
      }

      // ---- causal mask where this sub-tile overlaps a group's rows ----
      #pragma unroll
      for (int u = 0; u < 2; ++u)
        if (kv0 + 63 > wq0 + 16*u) {
          #pragma unroll
          for (int ni = 0; ni < 4; ++ni) {
            int kg = kv0 + ni*16 + fq*4;
            #pragma unroll
            for (int r = 0; r < 4; ++r)
              if (kg + r > myq[u]) sacc[u][ni][r] = -1e30f;
          }
        }

      // ---- P = exp2(S^T) into A-fragments ----
      bf16x8 pa[2][2];
      #pragma unroll
      for (int u = 0; u < 2; ++u)
        #pragma unroll
        for (int kk = 0; kk < 2; ++kk)
          #pragma unroll
          for (int e = 0; e < 8; ++e)
            pa[u][kk][e] = (bf16)__builtin_amdgcn_exp2f(sacc[u][2*kk + (e >> 2)][e & 3]);

      // ---- O += P @ V ; l += P @ 1 (V fragments shared across groups) ----
      #pragma unroll
      for (int kk = 0; kk < 2; ++kk) {
        bf16x8 bv[4];
        #pragma unroll
        for (int nf = 0; nf < 4; ++nf)
          bv[nf] = *(const bf16x8*)&Vs[cur][sub*4096 + (nf*16 + fr)*64 + (((4*kk + fq) ^ (fr & 7)) << 3)];
        __builtin_amdgcn_s_setprio(1);
        lacc[0] = __builtin_amdgcn_mfma_f32_16x16x32_bf16(pa[0][kk], ones, lacc[0], 0,0,0);
        lacc[1] = __builtin_amdgcn_mfma_f32_16x16x32_bf16(pa[1][kk], ones, lacc[1], 0,0,0);
        #pragma unroll
        for (int nf = 0; nf < 4; ++nf) {
          oacc[0][nf] = __builtin_amdgcn_mfma_f32_16x16x32_bf16(pa[0][kk], bv[nf], oacc[0][nf], 0,0,0);
          oacc[1][nf] = __builtin_amdgcn_mfma_f32_16x16x32_bf16(pa[1][kk], bv[nf], oacc[1][nf], 0,0,0);
        }
        __builtin_amdgcn_s_setprio(0);
      }
    }

    WAIT_VM0();
    __syncthreads();
    cur ^= 1;
  }
#undef ATTN_STAGE

  // ---- epilogue: lacc[u][r] is l for exactly oacc's row — no shuffles ----
  #pragma unroll
  for (int u = 0; u < 2; ++u) {
    const int row0 = wq0 + 16*u + fq*4;
    #pragma unroll
    for (int r = 0; r < 4; ++r) {
      float inv = 1.f / lacc[u][r];
      int s = row0 + r;
      #pragma unroll
      for (int nf = 0; nf < 4; ++nf)
        O[baseQ + (size_t)s*DD + nf*16 + fr] = (bf16)(oacc[u][nf][r] * inv);
    }
  }
}

// ---------------------------------------------------------------------------
extern "C" void kernel_launch(void* const* d_in, const int* in_sizes, int n_in,
                              void* d_out, int out_size, void* d_ws, size_t ws_size,
                              hipStream_t stream)
{
  const float* q   = (const float*)d_in[0];
  const float* k   = (const float*)d_in[1];
  const float* v   = (const float*)d_in[2];
  const float* w_q = (const float*)d_in[4];
  const float* w_k = (const float*)d_in[5];
  const float* w_v = (const float*)d_in[6];
  const float* w_o = (const float*)d_in[7];
  float* out = (float*)d_out;

  dim3 blk(256);
  const size_t need = ((size_t)4*NEL + (size_t)4*DD*DD) * sizeof(bf16); // ~41.9 MB

  if (ws_size >= need) {
    bf16* qb  = (bf16*)d_out;
    bf16* kb  = qb + NEL;
    bf16* vb  = (bf16*)d_ws;
    bf16* wqb = vb + NEL;
    bf16* wkb = wqb + DD*DD;
    bf16* wvb = wkb + DD*DD;
    bf16* wob = wvb + DD*DD;
    bf16* Qp  = wob + DD*DD;
    bf16* Kp  = Qp + NEL;
    bf16* Vtp = Kp + NEL;
    bf16* At  = vb;   // vb dead after V-projection

    cvt_all<<<dim3(512, 7), blk, 0, stream>>>(q, qb, k, kb, v, vb,
                                              w_q, wqb, w_k, wkb, w_v, wvb, w_o, wob);
    proj_qkv<<<dim3(16, 32, 3), blk, 0, stream>>>(
        qb, kb, vb, wqb, wkb, wvb, Qp, Kp, Vtp);
    attn_fwd<<<dim3(16, 32), blk, 0, stream>>>(Qp, Kp, Vtp, At);
    gemm_out<<<dim3(DD/64, (BB*SS)/128), blk, 0, stream>>>(At, wob, out);
  } else {
    bf16* Qp  = (bf16*)d_ws;
    bf16* Kp  = Qp + NEL;
    bf16* Vtp = Kp + NEL;
    bf16* At  = Qp;

    dim3 gg(DD/128, (BB*SS)/128);
    gemm_abt<true, 0><<<gg, blk, 0, stream>>>(q, w_q, Qp, QSCALE);
    gemm_abt<true, 0><<<gg, blk, 0, stream>>>(k, w_k, Kp, 1.0f);
    gemm_abt<true, 1><<<gg, blk, 0, stream>>>(v, w_v, Vtp, 1.0f);
    attn_fwd<<<dim3(16, 32), blk, 0, stream>>>(Qp, Kp, Vtp, At);
    gemm_abt<false, 2><<<gg, blk, 0, stream>>>(At, w_o, out, 1.0f);
  }
}